// Round 11
// baseline (355.687 us; speedup 1.0000x reference)
//
#include <hip/hip_runtime.h>
#include <hip/hip_bf16.h>
#include <math.h>

typedef unsigned short u16;
typedef __bf16 bf16x8_t __attribute__((ext_vector_type(8)));
typedef u16 u16x8 __attribute__((ext_vector_type(8)));
typedef u16 u16x4 __attribute__((ext_vector_type(4)));
typedef float f32x4 __attribute__((ext_vector_type(4)));

#define NH 12
#define LQ 2048
#define DM 768
#define DH 64
#define NR 4095           // 2L-1
#define LN2F 0.6931471805599453f

__device__ __forceinline__ u16 f2bf(float f){
  unsigned x = __float_as_uint(f);
  return (u16)((x + 0x7fffu + ((x >> 16) & 1u)) >> 16);   // RTNE
}
__device__ __forceinline__ float bf2f(u16 u){ return __uint_as_float(((unsigned)u) << 16); }

__device__ __forceinline__ f32x4 MFMA(u16x8 a, u16x8 b, f32x4 c){
  return __builtin_amdgcn_mfma_f32_16x16x32_bf16(
      __builtin_bit_cast(bf16x8_t, a), __builtin_bit_cast(bf16x8_t, b), c, 0, 0, 0);
}

// ---------------- gamma pdf table (unnormalized) + global max ----------------
__global__ void gamma_probs_kernel(float* __restrict__ gamtab,
                                   unsigned long long* __restrict__ gmax){
  int idx = blockIdx.x * 256 + threadIdx.x;   // 2048*128
  int x = idx >> 7, f = idx & 127;
  double fp1 = (double)(f + 1);
  double conc = 4.0 * fp1 * fp1;
  double rate = 0.25 * fp1;
  double xd = (double)x;
  double xlogy = (x > 0) ? (conc - 1.0) * log(xd) : 0.0;
  double logp = xlogy - rate * xd - lgamma(conc) + conc * log(rate);
  double p = exp(logp);
  gamtab[idx] = (float)p;
  double m = p;
  #pragma unroll
  for (int off = 1; off < 64; off <<= 1) m = fmax(m, __shfl_xor(m, off));
  if ((threadIdx.x & 63) == 0)
    atomicMax(gmax, (unsigned long long)__double_as_longlong(m));
}

// ---------------- positional encodings pe[4095][768] ----------------
__global__ void pe_kernel(const float* __restrict__ gamtab,
                          const unsigned long long* __restrict__ gmax,
                          float* __restrict__ pe){
  int idx = blockIdx.x * 256 + threadIdx.x;
  if (idx >= NR * DM) return;
  int p = idx / DM;
  int c = idx - p * DM;
  int f = c & 127;
  int kind = c >> 7;
  int pos = p - (LQ - 1);
  int apos = pos < 0 ? -pos : pos;
  float sgn = (pos > 0) ? 1.f : ((pos < 0) ? -1.f : 0.f);
  float v;
  int grp = kind >> 1;
  if (grp == 0){
    float hl = exp2f(3.f + 8.f * (float)f / 127.f);
    v = expf(-(LN2F / hl) * (float)apos);
  } else if (grp == 1){
    float cw = exp2f((float)(f + 1)) - 1.f;
    v = (cw > (float)apos) ? 1.f : 0.f;
  } else {
    float gm = (float)__longlong_as_double((long long)*gmax);
    v = gamtab[apos * 128 + f] / gm;
  }
  if (kind & 1) v *= sgn;
  pe[idx] = v;
}

// ---------------- fused q/k/v projection GEMM (grid.z picks input) ----------
#define GSTR 56
__launch_bounds__(256)
__global__ void proj3_kernel(const float* __restrict__ q_in, const float* __restrict__ k_in,
                             const float* __restrict__ v_in,
                             const float* __restrict__ Wq, const float* __restrict__ Wk,
                             const float* __restrict__ Wv,
                             u16* __restrict__ qh, u16* __restrict__ kh,
                             u16* __restrict__ vt){
  __shared__ u16 At[64 * GSTR];
  __shared__ u16 Wt[64 * GSTR];
  const int z = blockIdx.z;
  const float* A = (z == 0) ? q_in : (z == 1) ? k_in : v_in;
  const float* W = (z == 0) ? Wq : (z == 1) ? Wk : Wv;
  const float scale = (z == 0) ? 0.125f : 1.f;
  const int m0 = blockIdx.x * 64, n0 = blockIdx.y * 64;
  const int tid = threadIdx.x;
  const int w = tid >> 6, l = tid & 63, lr = l & 15, lg = l >> 4;
  const int moff = (w & 1) * 32, noff = (w >> 1) * 32;
  f32x4 acc[2][2] = {};
  const int arow = tid >> 2, akg = (tid & 3) * 8;
  const int wn = tid & 63, wkg = (tid >> 6) * 8;
  for (int k0 = 0; k0 < DM; k0 += 32){
    u16x8 av;
    {
      const float* ap = A + (size_t)(m0 + arow) * DM + k0 + akg;
      #pragma unroll
      for (int j = 0; j < 8; j++) av[j] = f2bf(ap[j]);
    }
    *(u16x8*)&At[arow * GSTR + akg] = av;
    u16x8 wv;
    #pragma unroll
    for (int i = 0; i < 8; i++)
      wv[i] = f2bf(W[(size_t)(k0 + wkg + i) * DM + n0 + wn]);
    *(u16x8*)&Wt[wn * GSTR + wkg] = wv;
    __syncthreads();
    u16x8 af0 = *(u16x8*)&At[(moff + lr) * GSTR + lg * 8];
    u16x8 af1 = *(u16x8*)&At[(moff + 16 + lr) * GSTR + lg * 8];
    u16x8 bf0 = *(u16x8*)&Wt[(noff + lr) * GSTR + lg * 8];
    u16x8 bf1 = *(u16x8*)&Wt[(noff + 16 + lr) * GSTR + lg * 8];
    acc[0][0] = MFMA(af0, bf0, acc[0][0]);
    acc[0][1] = MFMA(af0, bf1, acc[0][1]);
    acc[1][0] = MFMA(af1, bf0, acc[1][0]);
    acc[1][1] = MFMA(af1, bf1, acc[1][1]);
    __syncthreads();
  }
  u16* outb = (z == 0) ? qh : kh;
  #pragma unroll
  for (int mi = 0; mi < 2; mi++)
    #pragma unroll
    for (int ni = 0; ni < 2; ni++){
      if (z < 2){
        #pragma unroll
        for (int j = 0; j < 4; j++){
          int m = m0 + moff + mi * 16 + lg * 4 + j;
          int n = n0 + noff + ni * 16 + lr;
          outb[((size_t)(n >> 6) * LQ + m) * DH + (n & 63)] = f2bf(acc[mi][ni][j] * scale);
        }
      } else {
        int m = m0 + moff + mi * 16 + lg * 4;
        int n = n0 + noff + ni * 16 + lr;
        u16x4 ov;
        #pragma unroll
        for (int j = 0; j < 4; j++) ov[j] = f2bf(acc[mi][ni][j]);
        *(u16x4*)(vt + ((size_t)(n >> 6) * DH + (n & 63)) * LQ + m) = ov;
      }
    }
}

// ---------------- generic bf16-MFMA GEMM (rk + out-proj) ----------------
__launch_bounds__(256)
__global__ void gemm_kernel(const float* __restrict__ A, const float* __restrict__ W,
                            u16* __restrict__ outb, float* __restrict__ outf,
                            int M, float scale,
                            const float* __restrict__ bias, int mode){
  __shared__ u16 At[64 * GSTR];
  __shared__ u16 Wt[64 * GSTR];
  const int m0 = blockIdx.x * 64, n0 = blockIdx.y * 64;
  const int tid = threadIdx.x;
  const int w = tid >> 6, l = tid & 63, lr = l & 15, lg = l >> 4;
  const int moff = (w & 1) * 32, noff = (w >> 1) * 32;
  f32x4 acc[2][2] = {};
  const int arow = tid >> 2, akg = (tid & 3) * 8;
  const int wn = tid & 63, wkg = (tid >> 6) * 8;
  for (int k0 = 0; k0 < DM; k0 += 32){
    u16x8 av;
    if (m0 + arow < M){
      const float* ap = A + (size_t)(m0 + arow) * DM + k0 + akg;
      #pragma unroll
      for (int j = 0; j < 8; j++) av[j] = f2bf(ap[j]);
    } else {
      #pragma unroll
      for (int j = 0; j < 8; j++) av[j] = 0;
    }
    *(u16x8*)&At[arow * GSTR + akg] = av;
    u16x8 wv;
    #pragma unroll
    for (int i = 0; i < 8; i++)
      wv[i] = f2bf(W[(size_t)(k0 + wkg + i) * DM + n0 + wn]);
    *(u16x8*)&Wt[wn * GSTR + wkg] = wv;
    __syncthreads();
    u16x8 af0 = *(u16x8*)&At[(moff + lr) * GSTR + lg * 8];
    u16x8 af1 = *(u16x8*)&At[(moff + 16 + lr) * GSTR + lg * 8];
    u16x8 bf0 = *(u16x8*)&Wt[(noff + lr) * GSTR + lg * 8];
    u16x8 bf1 = *(u16x8*)&Wt[(noff + 16 + lr) * GSTR + lg * 8];
    acc[0][0] = MFMA(af0, bf0, acc[0][0]);
    acc[0][1] = MFMA(af0, bf1, acc[0][1]);
    acc[1][0] = MFMA(af1, bf0, acc[1][0]);
    acc[1][1] = MFMA(af1, bf1, acc[1][1]);
    __syncthreads();
  }
  #pragma unroll
  for (int mi = 0; mi < 2; mi++)
    #pragma unroll
    for (int ni = 0; ni < 2; ni++)
      #pragma unroll
      for (int j = 0; j < 4; j++){
        int m = m0 + moff + mi * 16 + lg * 4 + j;
        int n = n0 + noff + ni * 16 + lr;
        if (m < M){
          float v = acc[mi][ni][j] * scale;
          if (mode == 1){
            outf[(size_t)m * DM + n] = v + bias[n];
          } else {
            outb[((size_t)(n >> 6) * M + m) * DH + (n & 63)] = f2bf(v);
          }
        }
      }
}

// ---------------- fused rel-pos attention: rolled loops, two-sweep softmax ----
// Flat grid 1536, XCD-swizzled. One WG = 1 head x 16 q-rows, 8 waves; wave w
// owns k-slice [w*256,+256) and a private band slab [16][280] (cols kb..kb+272).
// Sweep 1: QK^T + slab gather -> running max (no S storage, rolled loop).
// Sweep 2: recompute QK^T + re-gather, exp -> P into slab (ordering safe:
// iter-nt P writes cols [nt*16, nt*16+15]; all band reads at iters >= nt target
// cols >= nt*16 and precede the write in program order within the wave).
#define QB 16
#define SSTR 280
#define SLAB (QB * SSTR)                       // u16 per wave slab
#define SMEM_ATTN (8 * SLAB * 2 + 1024)
__launch_bounds__(512, 4)
__global__ void attn_kernel(const u16* __restrict__ qh, const u16* __restrict__ kh,
                            const u16* __restrict__ vt, const u16* __restrict__ rk,
                            const int* __restrict__ mask,
                            const float* __restrict__ r_w, const float* __restrict__ r_r,
                            float* __restrict__ map, float* __restrict__ att){
  extern __shared__ char smem[];
  u16* RP = (u16*)smem;                         // 8 slabs
  float* redm = (float*)(smem + 8 * SLAB * 2);  // [8][16]
  float* redl = redm + 128;                     // [8][16]
  const int bid = blockIdx.x;
  const int swz = (bid & 7) * 192 + (bid >> 3); // XCD-aware: same head per XCD
  const int h = swz >> 7, q0 = (swz & 127) * QB;
  const int tid = threadIdx.x, w = tid >> 6, l = tid & 63, lr = l & 15, lg = l >> 4;
  const int roff = (LQ - 1) - q0 - (QB - 1);    // 2032 - q0
  const int kb = w * 256;
  u16* slab = RP + w * SLAB;

  // A fragments a1=(qh+r_w), a2=(qh+r_r)  (qh pre-scaled by 1/8)
  u16x8 a1[2], a2[2];
  #pragma unroll
  for (int kc = 0; kc < 2; kc++){
    u16x8 qv = *(const u16x8*)(qh + (size_t)(h * LQ + q0 + lr) * DH + kc * 32 + lg * 8);
    #pragma unroll
    for (int j = 0; j < 8; j++){
      int d = kc * 32 + lg * 8 + j;
      float f = bf2f(qv[j]);
      a1[kc][j] = f2bf(f + r_w[h * DH + d]);
      a2[kc][j] = f2bf(f + r_r[h * DH + d]);
    }
  }

  // loop 1 (rolled): band slab — 17 tiles covering cols [kb, kb+272)
  {
    const u16* rbase = rk + (size_t)h * NR * DH + lg * 8;
    int r = roff + kb + lr;
    u16* sp = slab + lg * 4 * SSTR + lr;
    #pragma unroll 1
    for (int t = 0; t < 17; t++){
      int rc = r > NR - 1 ? NR - 1 : r;
      const u16* rp = rbase + (size_t)rc * DH;
      u16x8 b0 = *(const u16x8*)(rp);
      u16x8 b1 = *(const u16x8*)(rp + 32);
      f32x4 racc = {};
      racc = MFMA(a2[0], b0, racc);
      racc = MFMA(a2[1], b1, racc);
      sp[0] = f2bf(racc[0]);
      sp[SSTR] = f2bf(racc[1]);
      sp[2 * SSTR] = f2bf(racc[2]);
      sp[3 * SSTR] = f2bf(racc[3]);
      r += 16;
      sp += 16;
    }
  }

  // sweep 1 (rolled): QK^T + gather + mask -> running max only
  float fm[4] = {-3.0e38f, -3.0e38f, -3.0e38f, -3.0e38f};
  unsigned mbits = 0;
  {
    const u16* kp = kh + (size_t)(h * LQ + kb + lr) * DH + lg * 8;
    const int* mp = mask + kb + lr;
    // gather base for row ql=lg*4+j at col offset (lr + 15 - ql)
    const u16* g0 = slab + (lg * 4 + 0) * SSTR + lr + 15 - (lg * 4 + 0);
    const u16* g1 = slab + (lg * 4 + 1) * SSTR + lr + 15 - (lg * 4 + 1);
    const u16* g2 = slab + (lg * 4 + 2) * SSTR + lr + 15 - (lg * 4 + 2);
    const u16* g3 = slab + (lg * 4 + 3) * SSTR + lr + 15 - (lg * 4 + 3);
    #pragma unroll 1
    for (int nt = 0; nt < 16; nt++){
      u16x8 b0 = *(const u16x8*)(kp);
      u16x8 b1 = *(const u16x8*)(kp + 32);
      f32x4 sv = {};
      sv = MFMA(a1[0], b0, sv);
      sv = MFMA(a1[1], b1, sv);
      int mv = mp[0];
      mbits |= ((unsigned)(mv & 1)) << nt;
      int co = nt * 16;
      float x0 = sv[0] + bf2f(g0[co]);
      float x1 = sv[1] + bf2f(g1[co]);
      float x2 = sv[2] + bf2f(g2[co]);
      float x3 = sv[3] + bf2f(g3[co]);
      if (mv != 1){
        fm[0] = fmaxf(fm[0], x0);
        fm[1] = fmaxf(fm[1], x1);
        fm[2] = fmaxf(fm[2], x2);
        fm[3] = fmaxf(fm[3], x3);
      }
      kp += 16 * DH;
      mp += 16;
    }
  }
  // masked-all-row guard: fall back to -10000 (the masked logit value)
  #pragma unroll
  for (int j = 0; j < 4; j++) fm[j] = fmaxf(fm[j], -10000.f);
  #pragma unroll
  for (int j = 0; j < 4; j++){
    float mx = fm[j];
    #pragma unroll
    for (int off = 1; off < 16; off <<= 1) mx = fmaxf(mx, __shfl_xor(mx, off));
    if (lr == 0) redm[w * QB + lg * 4 + j] = mx;
  }
  __syncthreads();
  #pragma unroll
  for (int j = 0; j < 4; j++){
    int ql = lg * 4 + j;
    float mx = redm[ql];
    #pragma unroll
    for (int w2 = 1; w2 < 8; w2++) mx = fmaxf(mx, redm[w2 * QB + ql]);
    fm[j] = mx;
  }

  // sweep 2 (rolled): recompute QK^T + re-gather, exp, sum, P -> slab
  float ls[4] = {0.f, 0.f, 0.f, 0.f};
  {
    const u16* kp = kh + (size_t)(h * LQ + kb + lr) * DH + lg * 8;
    const u16* g0 = slab + (lg * 4 + 0) * SSTR + lr + 15 - (lg * 4 + 0);
    const u16* g1 = slab + (lg * 4 + 1) * SSTR + lr + 15 - (lg * 4 + 1);
    const u16* g2 = slab + (lg * 4 + 2) * SSTR + lr + 15 - (lg * 4 + 2);
    const u16* g3 = slab + (lg * 4 + 3) * SSTR + lr + 15 - (lg * 4 + 3);
    u16* sp = slab + lg * 4 * SSTR + lr;
    #pragma unroll 1
    for (int nt = 0; nt < 16; nt++){
      u16x8 b0 = *(const u16x8*)(kp);
      u16x8 b1 = *(const u16x8*)(kp + 32);
      f32x4 sv = {};
      sv = MFMA(a1[0], b0, sv);
      sv = MFMA(a1[1], b1, sv);
      int msk = (mbits >> nt) & 1;
      int co = nt * 16;
      float x0 = msk ? -10000.f : sv[0] + bf2f(g0[co]);
      float x1 = msk ? -10000.f : sv[1] + bf2f(g1[co]);
      float x2 = msk ? -10000.f : sv[2] + bf2f(g2[co]);
      float x3 = msk ? -10000.f : sv[3] + bf2f(g3[co]);
      float p0 = __expf(x0 - fm[0]);
      float p1 = __expf(x1 - fm[1]);
      float p2 = __expf(x2 - fm[2]);
      float p3 = __expf(x3 - fm[3]);
      ls[0] += p0; ls[1] += p1; ls[2] += p2; ls[3] += p3;
      sp[co] = f2bf(p0);
      sp[co + SSTR] = f2bf(p1);
      sp[co + 2 * SSTR] = f2bf(p2);
      sp[co + 3 * SSTR] = f2bf(p3);
      kp += 16 * DH;
    }
  }
  #pragma unroll
  for (int j = 0; j < 4; j++){
    float sum = ls[j];
    #pragma unroll
    for (int off = 1; off < 16; off <<= 1) sum += __shfl_xor(sum, off);
    if (lr == 0) redl[w * QB + lg * 4 + j] = sum;
  }
  __syncthreads();
  float inv[4];
  #pragma unroll
  for (int j = 0; j < 4; j++){
    int ql = lg * 4 + j;
    float d = redl[ql];
    #pragma unroll
    for (int w2 = 1; w2 < 8; w2++) d += redl[w2 * QB + ql];
    inv[j] = 1.f / d;
  }

  // normalized map write (rolled) — before PV so stores drain under MFMA
  {
    int qrow = tid >> 5, cb = (tid & 31) * 8;
    float dsum = redl[qrow];
    #pragma unroll
    for (int w2 = 1; w2 < 8; w2++) dsum += redl[w2 * QB + qrow];
    float invr = 1.f / dsum;
    float* mp2 = map + (size_t)(h * LQ + q0 + qrow) * LQ + cb;
    const u16* pp = RP + qrow * SSTR + cb;
    #pragma unroll 1
    for (int it = 0; it < 8; it++){
      u16x8 pv = *(const u16x8*)pp;
      f32x4 o0, o1;
      #pragma unroll
      for (int j = 0; j < 4; j++){
        o0[j] = bf2f(pv[j]) * invr;
        o1[j] = bf2f(pv[4 + j]) * invr;
      }
      *(f32x4*)(mp2) = o0;
      *(f32x4*)(mp2 + 4) = o1;
      pp += SLAB;
      mp2 += 256;
    }
  }

  // PV (rolled over k-chunks; o[4] static)
  f32x4 o[4] = {};
  {
    const u16* pa_p = slab + lr * SSTR + lg * 8;
    const u16* v0 = vt + (size_t)(h * DH + 0 * 16 + lr) * LQ + kb + lg * 8;
    const u16* v1 = vt + (size_t)(h * DH + 1 * 16 + lr) * LQ + kb + lg * 8;
    const u16* v2 = vt + (size_t)(h * DH + 2 * 16 + lr) * LQ + kb + lg * 8;
    const u16* v3 = vt + (size_t)(h * DH + 3 * 16 + lr) * LQ + kb + lg * 8;
    #pragma unroll 1
    for (int kc2 = 0; kc2 < 8; kc2++){
      u16x8 pa = *(const u16x8*)pa_p;
      o[0] = MFMA(pa, *(const u16x8*)v0, o[0]);
      o[1] = MFMA(pa, *(const u16x8*)v1, o[1]);
      o[2] = MFMA(pa, *(const u16x8*)v2, o[2]);
      o[3] = MFMA(pa, *(const u16x8*)v3, o[3]);
      pa_p += 32; v0 += 32; v1 += 32; v2 += 32; v3 += 32;
    }
  }
  __syncthreads();

  // cross-wave O reduction (overlays slabs)
  float* Op = (float*)smem;    // [8][16][64]
  #pragma unroll
  for (int ni = 0; ni < 4; ni++)
    #pragma unroll
    for (int j = 0; j < 4; j++)
      Op[(w * QB + lg * 4 + j) * 64 + ni * 16 + lr] = o[ni][j] * inv[j];
  __syncthreads();
  {
    int q = tid >> 5, dg = (tid & 31) * 2;
    float acc0 = 0.f, acc1 = 0.f;
    #pragma unroll
    for (int w2 = 0; w2 < 8; w2++){
      acc0 += Op[(w2 * QB + q) * 64 + dg];
      acc1 += Op[(w2 * QB + q) * 64 + dg + 1];
    }
    float* ap = att + (size_t)(q0 + q) * DM + h * DH + dg;
    ap[0] = acc0;
    ap[1] = acc1;
  }
}

extern "C" void kernel_launch(void* const* d_in, const int* in_sizes, int n_in,
                              void* d_out, int out_size, void* d_ws, size_t ws_size,
                              hipStream_t stream){
  const float* v_in = (const float*)d_in[0];
  const float* k_in = (const float*)d_in[1];
  const float* q_in = (const float*)d_in[2];
  const int*   mask = (const int*)d_in[3];
  const float* Wq   = (const float*)d_in[4];
  const float* Wk   = (const float*)d_in[5];
  const float* Wv   = (const float*)d_in[6];
  const float* Wrk  = (const float*)d_in[7];
  const float* r_w  = (const float*)d_in[8];
  const float* r_r  = (const float*)d_in[9];
  const float* Wo   = (const float*)d_in[10];
  const float* bo   = (const float*)d_in[11];

  char* ws = (char*)d_ws;
  u16* qh = (u16*)(ws + 0);              // [12][2048][64] bf16
  u16* kh = (u16*)(ws + 3145728);
  u16* vt = (u16*)(ws + 6291456);        // [12][64][2048] bf16
  u16* rk = (u16*)(ws + 9437184);        // [12][4095][64] bf16
  float* pe = (float*)(ws + 15727104);   // [4095][768] f32
  float* att = (float*)(ws + 28306944);  // [2048][768] f32
  float* gamtab = (float*)(ws + 34598400);           // [2048][128] f32
  unsigned long long* gmax = (unsigned long long*)(ws + 35646976);

  float* out0 = (float*)d_out;                     // [2048][768] f32
  float* map  = out0 + (size_t)LQ * DM;            // [12][2048][2048] f32

  hipMemsetAsync(gmax, 0, 8, stream);
  gamma_probs_kernel<<<1024, 256, 0, stream>>>(gamtab, gmax);
  pe_kernel<<<(NR * DM + 255) / 256, 256, 0, stream>>>(gamtab, gmax, pe);

  proj3_kernel<<<dim3(32, 12, 3), 256, 0, stream>>>(q_in, k_in, v_in, Wq, Wk, Wv,
                                                    qh, kh, vt);
  gemm_kernel<<<dim3(64, 12), 256, 0, stream>>>(pe, Wrk, rk, nullptr, NR, 1.f, nullptr, 0);

  hipFuncSetAttribute((const void*)attn_kernel,
                      hipFuncAttributeMaxDynamicSharedMemorySize, SMEM_ATTN);
  attn_kernel<<<dim3((LQ / QB) * NH), 512, SMEM_ATTN, stream>>>(qh, kh, vt, rk, mask,
                                                                r_w, r_r, map, att);
  gemm_kernel<<<dim3(32, 12), 256, 0, stream>>>(att, Wo, nullptr, out0, LQ, 1.f, bo, 1);
}

// Round 12
// 334.250 us; speedup vs baseline: 1.0641x; 1.0641x over previous
//
#include <hip/hip_runtime.h>
#include <hip/hip_bf16.h>
#include <math.h>

typedef unsigned short u16;
typedef __bf16 bf16x8_t __attribute__((ext_vector_type(8)));
typedef u16 u16x8 __attribute__((ext_vector_type(8)));
typedef u16 u16x4 __attribute__((ext_vector_type(4)));
typedef float f32x4 __attribute__((ext_vector_type(4)));

#define NH 12
#define LQ 2048
#define DM 768
#define DH 64
#define NR 4095           // 2L-1
#define LN2F 0.6931471805599453f

__device__ __forceinline__ u16 f2bf(float f){
  unsigned x = __float_as_uint(f);
  return (u16)((x + 0x7fffu + ((x >> 16) & 1u)) >> 16);   // RTNE
}
__device__ __forceinline__ float bf2f(u16 u){ return __uint_as_float(((unsigned)u) << 16); }

__device__ __forceinline__ f32x4 MFMA(u16x8 a, u16x8 b, f32x4 c){
  return __builtin_amdgcn_mfma_f32_16x16x32_bf16(
      __builtin_bit_cast(bf16x8_t, a), __builtin_bit_cast(bf16x8_t, b), c, 0, 0, 0);
}

// ---------------- gamma tables: logx[2048] f64, Cf[128] f64 ----------------
__global__ void gamma_tables_kernel(double* __restrict__ logx, double* __restrict__ Cf){
  int i = blockIdx.x * 256 + threadIdx.x;
  if (i < 2048) logx[i] = (i > 0) ? log((double)i) : 0.0;
  if (i < 128){
    double fp1 = (double)(i + 1);
    double conc = 4.0 * fp1 * fp1;
    double rate = 0.25 * fp1;
    Cf[i] = conc * log(rate) - lgamma(conc);
  }
}

// ---------------- gamma pdf table (unnormalized) + global max ----------------
__global__ void gamma_probs_kernel(const double* __restrict__ logx,
                                   const double* __restrict__ Cf,
                                   float* __restrict__ gamtab,
                                   unsigned long long* __restrict__ gmax){
  int idx = blockIdx.x * 256 + threadIdx.x;   // 2048*128
  int x = idx >> 7, f = idx & 127;
  double fp1 = (double)(f + 1);
  double conc = 4.0 * fp1 * fp1;
  double rate = 0.25 * fp1;
  double xl = (x > 0) ? (conc - 1.0) * logx[x] : 0.0;   // xlogy(a,0)=0
  double p = exp(xl - rate * (double)x + Cf[f]);
  gamtab[idx] = (float)p;
  double m = p;
  #pragma unroll
  for (int off = 1; off < 64; off <<= 1) m = fmax(m, __shfl_xor(m, off));
  if ((threadIdx.x & 63) == 0)
    atomicMax(gmax, (unsigned long long)__double_as_longlong(m));
}

// ---------------- positional encodings pe[4095][768] ----------------
__global__ void pe_kernel(const float* __restrict__ gamtab,
                          const unsigned long long* __restrict__ gmax,
                          float* __restrict__ pe){
  int idx = blockIdx.x * 256 + threadIdx.x;
  if (idx >= NR * DM) return;
  int p = idx / DM;
  int c = idx - p * DM;
  int f = c & 127;
  int kind = c >> 7;
  int pos = p - (LQ - 1);
  int apos = pos < 0 ? -pos : pos;
  float sgn = (pos > 0) ? 1.f : ((pos < 0) ? -1.f : 0.f);
  float v;
  int grp = kind >> 1;
  if (grp == 0){
    float hl = exp2f(3.f + 8.f * (float)f / 127.f);
    v = expf(-(LN2F / hl) * (float)apos);
  } else if (grp == 1){
    float cw = exp2f((float)(f + 1)) - 1.f;
    v = (cw > (float)apos) ? 1.f : 0.f;
  } else {
    float gm = (float)__longlong_as_double((long long)*gmax);
    v = gamtab[apos * 128 + f] / gm;
  }
  if (kind & 1) v *= sgn;
  pe[idx] = v;
}

// ---------------- fused q/k/v projection GEMM, BK=64 (grid.z picks input) ----
#define GSTRB 72   // 64 k + 8 pad (144 B rows, 16B-aligned)
__launch_bounds__(256)
__global__ void proj3_kernel(const float* __restrict__ q_in, const float* __restrict__ k_in,
                             const float* __restrict__ v_in,
                             const float* __restrict__ Wq, const float* __restrict__ Wk,
                             const float* __restrict__ Wv,
                             u16* __restrict__ qh, u16* __restrict__ kh,
                             u16* __restrict__ vt){
  __shared__ u16 At[64 * GSTRB];
  __shared__ u16 Wt[64 * GSTRB];
  const int z = blockIdx.z;
  const float* A = (z == 0) ? q_in : (z == 1) ? k_in : v_in;
  const float* W = (z == 0) ? Wq : (z == 1) ? Wk : Wv;
  const float scale = (z == 0) ? 0.125f : 1.f;
  const int m0 = blockIdx.x * 64, n0 = blockIdx.y * 64;
  const int tid = threadIdx.x;
  const int w = tid >> 6, l = tid & 63, lr = l & 15, lg = l >> 4;
  const int moff = (w & 1) * 32, noff = (w >> 1) * 32;
  f32x4 acc[2][2] = {};
  const int arow = tid >> 2, akg = (tid & 3) * 16;
  const int wn = tid & 63, wkg = (tid >> 6) * 16;
  for (int k0 = 0; k0 < DM; k0 += 64){
    u16x8 av0, av1;
    {
      const float* ap = A + (size_t)(m0 + arow) * DM + k0 + akg;
      #pragma unroll
      for (int j = 0; j < 8; j++){ av0[j] = f2bf(ap[j]); av1[j] = f2bf(ap[8 + j]); }
    }
    *(u16x8*)&At[arow * GSTRB + akg] = av0;
    *(u16x8*)&At[arow * GSTRB + akg + 8] = av1;
    u16x8 wv0, wv1;
    #pragma unroll
    for (int i = 0; i < 8; i++){
      wv0[i] = f2bf(W[(size_t)(k0 + wkg + i) * DM + n0 + wn]);
      wv1[i] = f2bf(W[(size_t)(k0 + wkg + 8 + i) * DM + n0 + wn]);
    }
    *(u16x8*)&Wt[wn * GSTRB + wkg] = wv0;
    *(u16x8*)&Wt[wn * GSTRB + wkg + 8] = wv1;
    __syncthreads();
    #pragma unroll
    for (int kc = 0; kc < 2; kc++){
      u16x8 af0 = *(u16x8*)&At[(moff + lr) * GSTRB + kc * 32 + lg * 8];
      u16x8 af1 = *(u16x8*)&At[(moff + 16 + lr) * GSTRB + kc * 32 + lg * 8];
      u16x8 bf0 = *(u16x8*)&Wt[(noff + lr) * GSTRB + kc * 32 + lg * 8];
      u16x8 bf1 = *(u16x8*)&Wt[(noff + 16 + lr) * GSTRB + kc * 32 + lg * 8];
      acc[0][0] = MFMA(af0, bf0, acc[0][0]);
      acc[0][1] = MFMA(af0, bf1, acc[0][1]);
      acc[1][0] = MFMA(af1, bf0, acc[1][0]);
      acc[1][1] = MFMA(af1, bf1, acc[1][1]);
    }
    __syncthreads();
  }
  u16* outb = (z == 0) ? qh : kh;
  #pragma unroll
  for (int mi = 0; mi < 2; mi++)
    #pragma unroll
    for (int ni = 0; ni < 2; ni++){
      if (z < 2){
        #pragma unroll
        for (int j = 0; j < 4; j++){
          int m = m0 + moff + mi * 16 + lg * 4 + j;
          int n = n0 + noff + ni * 16 + lr;
          outb[((size_t)(n >> 6) * LQ + m) * DH + (n & 63)] = f2bf(acc[mi][ni][j] * scale);
        }
      } else {
        int m = m0 + moff + mi * 16 + lg * 4;
        int n = n0 + noff + ni * 16 + lr;
        u16x4 ov;
        #pragma unroll
        for (int j = 0; j < 4; j++) ov[j] = f2bf(acc[mi][ni][j]);
        *(u16x4*)(vt + ((size_t)(n >> 6) * DH + (n & 63)) * LQ + m) = ov;
      }
    }
}

// ---------------- generic bf16-MFMA GEMM, BK=64 (rk + out-proj) ----------------
__launch_bounds__(256)
__global__ void gemm_kernel(const float* __restrict__ A, const float* __restrict__ W,
                            u16* __restrict__ outb, float* __restrict__ outf,
                            int M, float scale,
                            const float* __restrict__ bias, int mode){
  __shared__ u16 At[64 * GSTRB];
  __shared__ u16 Wt[64 * GSTRB];
  const int m0 = blockIdx.x * 64, n0 = blockIdx.y * 64;
  const int tid = threadIdx.x;
  const int w = tid >> 6, l = tid & 63, lr = l & 15, lg = l >> 4;
  const int moff = (w & 1) * 32, noff = (w >> 1) * 32;
  f32x4 acc[2][2] = {};
  const int arow = tid >> 2, akg = (tid & 3) * 16;
  const int wn = tid & 63, wkg = (tid >> 6) * 16;
  for (int k0 = 0; k0 < DM; k0 += 64){
    u16x8 av0, av1;
    if (m0 + arow < M){
      const float* ap = A + (size_t)(m0 + arow) * DM + k0 + akg;
      #pragma unroll
      for (int j = 0; j < 8; j++){ av0[j] = f2bf(ap[j]); av1[j] = f2bf(ap[8 + j]); }
    } else {
      #pragma unroll
      for (int j = 0; j < 8; j++){ av0[j] = 0; av1[j] = 0; }
    }
    *(u16x8*)&At[arow * GSTRB + akg] = av0;
    *(u16x8*)&At[arow * GSTRB + akg + 8] = av1;
    u16x8 wv0, wv1;
    #pragma unroll
    for (int i = 0; i < 8; i++){
      wv0[i] = f2bf(W[(size_t)(k0 + wkg + i) * DM + n0 + wn]);
      wv1[i] = f2bf(W[(size_t)(k0 + wkg + 8 + i) * DM + n0 + wn]);
    }
    *(u16x8*)&Wt[wn * GSTRB + wkg] = wv0;
    *(u16x8*)&Wt[wn * GSTRB + wkg + 8] = wv1;
    __syncthreads();
    #pragma unroll
    for (int kc = 0; kc < 2; kc++){
      u16x8 af0 = *(u16x8*)&At[(moff + lr) * GSTRB + kc * 32 + lg * 8];
      u16x8 af1 = *(u16x8*)&At[(moff + 16 + lr) * GSTRB + kc * 32 + lg * 8];
      u16x8 bf0 = *(u16x8*)&Wt[(noff + lr) * GSTRB + kc * 32 + lg * 8];
      u16x8 bf1 = *(u16x8*)&Wt[(noff + 16 + lr) * GSTRB + kc * 32 + lg * 8];
      acc[0][0] = MFMA(af0, bf0, acc[0][0]);
      acc[0][1] = MFMA(af0, bf1, acc[0][1]);
      acc[1][0] = MFMA(af1, bf0, acc[1][0]);
      acc[1][1] = MFMA(af1, bf1, acc[1][1]);
    }
    __syncthreads();
  }
  #pragma unroll
  for (int mi = 0; mi < 2; mi++)
    #pragma unroll
    for (int ni = 0; ni < 2; ni++)
      #pragma unroll
      for (int j = 0; j < 4; j++){
        int m = m0 + moff + mi * 16 + lg * 4 + j;
        int n = n0 + noff + ni * 16 + lr;
        if (m < M){
          float v = acc[mi][ni][j] * scale;
          if (mode == 1){
            outf[(size_t)m * DM + n] = v + bias[n];
          } else {
            outb[((size_t)(n >> 6) * M + m) * DH + (n & 63)] = f2bf(v);
          }
        }
      }
}

// ---------------- fused rel-pos attention: map write AFTER last barrier -------
// Flat grid 1536, XCD-swizzled. One WG = 1 head x 16 q-rows, 8 waves; wave w
// owns k-slice [w*256,+256) + private band slab [16][280]. S in AGPRs.
// Op reduction in a SEPARATE LDS region (no slab overlay) so the 201 MB map
// write can happen after the final barrier — no __syncthreads ever drains it.
#define QB 16
#define SSTR 280
#define SLAB (QB * SSTR)                        // u16 per wave slab
#define OPOFF (8 * SLAB * 2 + 1024)
#define SMEM_ATTN (OPOFF + 32768)               // 105472 B -> 1 WG/CU
__launch_bounds__(512, 2)
__global__ void attn_kernel(const u16* __restrict__ qh, const u16* __restrict__ kh,
                            const u16* __restrict__ vt, const u16* __restrict__ rk,
                            const int* __restrict__ mask,
                            const float* __restrict__ r_w, const float* __restrict__ r_r,
                            float* __restrict__ map, float* __restrict__ att){
  extern __shared__ char smem[];
  u16* RP = (u16*)smem;                         // 8 slabs
  float* redm = (float*)(smem + 8 * SLAB * 2);  // [8][16]
  float* redl = redm + 128;                     // [8][16]
  float* Op = (float*)(smem + OPOFF);           // [8][16][64]
  const int bid = blockIdx.x;
  const int swz = (bid & 7) * 192 + (bid >> 3); // XCD-aware: same head per XCD
  const int h = swz >> 7, q0 = (swz & 127) * QB;
  const int tid = threadIdx.x, w = tid >> 6, l = tid & 63, lr = l & 15, lg = l >> 4;
  const int roff = (LQ - 1) - q0 - (QB - 1);    // 2032 - q0
  const int kb = w * 256;
  u16* slab = RP + w * SLAB;

  // A fragments a1=(qh+r_w), a2=(qh+r_r)  (qh pre-scaled by 1/8)
  u16x8 a1[2], a2[2];
  #pragma unroll
  for (int kc = 0; kc < 2; kc++){
    u16x8 qv = *(const u16x8*)(qh + (size_t)(h * LQ + q0 + lr) * DH + kc * 32 + lg * 8);
    #pragma unroll
    for (int j = 0; j < 8; j++){
      int d = kc * 32 + lg * 8 + j;
      float f = bf2f(qv[j]);
      a1[kc][j] = f2bf(f + r_w[h * DH + d]);
      a2[kc][j] = f2bf(f + r_r[h * DH + d]);
    }
  }

  // loop 1: band slab — 17 tiles covering cols [kb, kb+272)
  #pragma unroll 4
  for (int t = 0; t < 17; t++){
    int r = roff + kb + t * 16 + lr;
    if (r > NR - 1) r = NR - 1;                 // never-gathered corner only
    const u16* rp = rk + (size_t)(h * NR + r) * DH + lg * 8;
    u16x8 b0 = *(const u16x8*)(rp);
    u16x8 b1 = *(const u16x8*)(rp + 32);
    f32x4 racc = {};
    racc = MFMA(a2[0], b0, racc);
    racc = MFMA(a2[1], b1, racc);
    #pragma unroll
    for (int j = 0; j < 4; j++)
      slab[(lg * 4 + j) * SSTR + t * 16 + lr] = f2bf(racc[j]);
  }
  __asm__ volatile("s_waitcnt lgkmcnt(0)" ::: "memory");   // wave-local slab ready
  __builtin_amdgcn_sched_barrier(0);

  // loop 2: content logits + wave-local band gather + mask -> S in AGPRs
  f32x4 s[16];
  #pragma unroll
  for (int nt = 0; nt < 16; nt++){
    const u16* kp = kh + (size_t)(h * LQ + kb + nt * 16 + lr) * DH + lg * 8;
    u16x8 b0 = *(const u16x8*)(kp);
    u16x8 b1 = *(const u16x8*)(kp + 32);
    f32x4 sv = {};
    sv = MFMA(a1[0], b0, sv);
    sv = MFMA(a1[1], b1, sv);
    int mv = mask[kb + nt * 16 + lr];
    #pragma unroll
    for (int j = 0; j < 4; j++){
      int ql = lg * 4 + j;
      float x = sv[j] + bf2f(slab[ql * SSTR + nt * 16 + lr + 15 - ql]);
      sv[j] = (mv == 1) ? -10000.f : x;
    }
    s[nt] = sv;
  }

  // softmax max reduce
  float fm[4];
  #pragma unroll
  for (int j = 0; j < 4; j++){
    float mx = -3.0e38f;
    #pragma unroll
    for (int nt = 0; nt < 16; nt++) mx = fmaxf(mx, s[nt][j]);
    #pragma unroll
    for (int off = 1; off < 16; off <<= 1) mx = fmaxf(mx, __shfl_xor(mx, off));
    if (lr == 0) redm[w * QB + lg * 4 + j] = mx;
  }
  __syncthreads();
  #pragma unroll
  for (int j = 0; j < 4; j++){
    int ql = lg * 4 + j;
    float mx = redm[ql];
    #pragma unroll
    for (int w2 = 1; w2 < 8; w2++) mx = fmaxf(mx, redm[w2 * QB + ql]);
    fm[j] = mx;
  }

  // exp + P store (overwrites band in own slab; band fully consumed)
  float ls[4] = {0.f, 0.f, 0.f, 0.f};
  #pragma unroll
  for (int nt = 0; nt < 16; nt++)
    #pragma unroll
    for (int j = 0; j < 4; j++){
      float p = __expf(s[nt][j] - fm[j]);
      ls[j] += p;
      slab[(lg * 4 + j) * SSTR + nt * 16 + lr] = f2bf(p);
    }
  #pragma unroll
  for (int j = 0; j < 4; j++){
    float sum = ls[j];
    #pragma unroll
    for (int off = 1; off < 16; off <<= 1) sum += __shfl_xor(sum, off);
    if (lr == 0) redl[w * QB + lg * 4 + j] = sum;
  }
  __syncthreads();                               // P + redl visible to all
  float inv[4];
  #pragma unroll
  for (int j = 0; j < 4; j++){
    int ql = lg * 4 + j;
    float d = redl[ql];
    #pragma unroll
    for (int w2 = 1; w2 < 8; w2++) d += redl[w2 * QB + ql];
    inv[j] = 1.f / d;
  }

  // PV (A-frags = P rows from own slab, B-frags = vt[h][d][k] contiguous)
  f32x4 o[4] = {};
  #pragma unroll
  for (int kc2 = 0; kc2 < 8; kc2++){
    u16x8 pa = *(u16x8*)&slab[lr * SSTR + kc2 * 32 + lg * 8];
    #pragma unroll
    for (int ni = 0; ni < 4; ni++){
      u16x8 vv = *(const u16x8*)(vt + (size_t)(h * DH + ni * 16 + lr) * LQ + kb + kc2 * 32 + lg * 8);
      o[ni] = MFMA(pa, vv, o[ni]);
    }
  }

  // cross-wave O reduction in the separate Op region (slabs stay intact)
  #pragma unroll
  for (int ni = 0; ni < 4; ni++)
    #pragma unroll
    for (int j = 0; j < 4; j++)
      Op[(w * QB + lg * 4 + j) * 64 + ni * 16 + lr] = o[ni][j] * inv[j];
  __syncthreads();                               // LAST barrier
  {
    int q = tid >> 5, dg = (tid & 31) * 2;
    float acc0 = 0.f, acc1 = 0.f;
    #pragma unroll
    for (int w2 = 0; w2 < 8; w2++){
      acc0 += Op[(w2 * QB + q) * 64 + dg];
      acc1 += Op[(w2 * QB + q) * 64 + dg + 1];
    }
    float* ap = att + (size_t)(q0 + q) * DM + h * DH + dg;
    ap[0] = acc0;
    ap[1] = acc1;
  }

  // normalized map write (f32, output 1) — after the last barrier; stores
  // retire as waves end, never drained by a workgroup barrier.
  {
    int qrow = tid >> 5, cb = (tid & 31) * 8;
    float dsum = redl[qrow];
    #pragma unroll
    for (int w2 = 1; w2 < 8; w2++) dsum += redl[w2 * QB + qrow];
    float invr = 1.f / dsum;
    float* mrow = map + (size_t)(h * LQ + q0 + qrow) * LQ;
    #pragma unroll
    for (int it = 0; it < 8; it++){
      u16x8 pv = *(u16x8*)&RP[it * SLAB + qrow * SSTR + cb];
      f32x4 o0, o1;
      #pragma unroll
      for (int j = 0; j < 4; j++){
        o0[j] = bf2f(pv[j]) * invr;
        o1[j] = bf2f(pv[4 + j]) * invr;
      }
      int c = cb + it * 256;
      *(f32x4*)(mrow + c) = o0;
      *(f32x4*)(mrow + c + 4) = o1;
    }
  }
}

extern "C" void kernel_launch(void* const* d_in, const int* in_sizes, int n_in,
                              void* d_out, int out_size, void* d_ws, size_t ws_size,
                              hipStream_t stream){
  const float* v_in = (const float*)d_in[0];
  const float* k_in = (const float*)d_in[1];
  const float* q_in = (const float*)d_in[2];
  const int*   mask = (const int*)d_in[3];
  const float* Wq   = (const float*)d_in[4];
  const float* Wk   = (const float*)d_in[5];
  const float* Wv   = (const float*)d_in[6];
  const float* Wrk  = (const float*)d_in[7];
  const float* r_w  = (const float*)d_in[8];
  const float* r_r  = (const float*)d_in[9];
  const float* Wo   = (const float*)d_in[10];
  const float* bo   = (const float*)d_in[11];

  char* ws = (char*)d_ws;
  u16* qh = (u16*)(ws + 0);              // [12][2048][64] bf16
  u16* kh = (u16*)(ws + 3145728);
  u16* vt = (u16*)(ws + 6291456);        // [12][64][2048] bf16
  u16* rk = (u16*)(ws + 9437184);        // [12][4095][64] bf16
  float* pe = (float*)(ws + 15727104);   // [4095][768] f32
  float* att = (float*)(ws + 28306944);  // [2048][768] f32
  float* gamtab = (float*)(ws + 34598400);           // [2048][128] f32
  unsigned long long* gmax = (unsigned long long*)(ws + 35646976);
  double* logx = (double*)(ws + 35647040);           // [2048] f64
  double* Cf   = (double*)(ws + 35663424);           // [128] f64

  float* out0 = (float*)d_out;                     // [2048][768] f32
  float* map  = out0 + (size_t)LQ * DM;            // [12][2048][2048] f32

  hipMemsetAsync(gmax, 0, 8, stream);
  gamma_tables_kernel<<<8, 256, 0, stream>>>(logx, Cf);
  gamma_probs_kernel<<<1024, 256, 0, stream>>>(logx, Cf, gamtab, gmax);
  pe_kernel<<<(NR * DM + 255) / 256, 256, 0, stream>>>(gamtab, gmax, pe);

  proj3_kernel<<<dim3(32, 12, 3), 256, 0, stream>>>(q_in, k_in, v_in, Wq, Wk, Wv,
                                                    qh, kh, vt);
  gemm_kernel<<<dim3(64, 12), 256, 0, stream>>>(pe, Wrk, rk, nullptr, NR, 1.f, nullptr, 0);

  hipFuncSetAttribute((const void*)attn_kernel,
                      hipFuncAttributeMaxDynamicSharedMemorySize, SMEM_ATTN);
  attn_kernel<<<dim3((LQ / QB) * NH), 512, SMEM_ATTN, stream>>>(qh, kh, vt, rk, mask,
                                                                r_w, r_r, map, att);
  gemm_kernel<<<dim3(32, 12), 256, 0, stream>>>(att, Wo, nullptr, out0, LQ, 1.f, bo, 1);
}

// Round 13
// 312.538 us; speedup vs baseline: 1.1381x; 1.0695x over previous
//
#include <hip/hip_runtime.h>
#include <hip/hip_bf16.h>
#include <math.h>

typedef unsigned short u16;
typedef __bf16 bf16x8_t __attribute__((ext_vector_type(8)));
typedef u16 u16x8 __attribute__((ext_vector_type(8)));
typedef u16 u16x4 __attribute__((ext_vector_type(4)));
typedef float f32x4 __attribute__((ext_vector_type(4)));

#define NH 12
#define LQ 2048
#define DM 768
#define DH 64
#define NR 4095           // 2L-1
#define LN2F 0.6931471805599453f

__device__ __forceinline__ u16 f2bf(float f){
  unsigned x = __float_as_uint(f);
  return (u16)((x + 0x7fffu + ((x >> 16) & 1u)) >> 16);   // RTNE
}
__device__ __forceinline__ float bf2f(u16 u){ return __uint_as_float(((unsigned)u) << 16); }

__device__ __forceinline__ f32x4 MFMA(u16x8 a, u16x8 b, f32x4 c){
  return __builtin_amdgcn_mfma_f32_16x16x32_bf16(
      __builtin_bit_cast(bf16x8_t, a), __builtin_bit_cast(bf16x8_t, b), c, 0, 0, 0);
}

// ---------------- gamma pdf table (unnormalized) + global max ----------------
__global__ void gamma_probs_kernel(float* __restrict__ gamtab,
                                   unsigned long long* __restrict__ gmax){
  int idx = blockIdx.x * 256 + threadIdx.x;   // 2048*128
  int x = idx >> 7, f = idx & 127;
  double fp1 = (double)(f + 1);
  double conc = 4.0 * fp1 * fp1;
  double rate = 0.25 * fp1;
  double xd = (double)x;
  double xlogy = (x > 0) ? (conc - 1.0) * log(xd) : 0.0;
  double logp = xlogy - rate * xd - lgamma(conc) + conc * log(rate);
  double p = exp(logp);
  gamtab[idx] = (float)p;
  double m = p;
  #pragma unroll
  for (int off = 1; off < 64; off <<= 1) m = fmax(m, __shfl_xor(m, off));
  if ((threadIdx.x & 63) == 0)
    atomicMax(gmax, (unsigned long long)__double_as_longlong(m));
}

// ---------------- positional encodings pe[4095][768] ----------------
__global__ void pe_kernel(const float* __restrict__ gamtab,
                          const unsigned long long* __restrict__ gmax,
                          float* __restrict__ pe){
  int idx = blockIdx.x * 256 + threadIdx.x;
  if (idx >= NR * DM) return;
  int p = idx / DM;
  int c = idx - p * DM;
  int f = c & 127;
  int kind = c >> 7;
  int pos = p - (LQ - 1);
  int apos = pos < 0 ? -pos : pos;
  float sgn = (pos > 0) ? 1.f : ((pos < 0) ? -1.f : 0.f);
  float v;
  int grp = kind >> 1;
  if (grp == 0){
    float hl = exp2f(3.f + 8.f * (float)f / 127.f);
    v = expf(-(LN2F / hl) * (float)apos);
  } else if (grp == 1){
    float cw = exp2f((float)(f + 1)) - 1.f;
    v = (cw > (float)apos) ? 1.f : 0.f;
  } else {
    float gm = (float)__longlong_as_double((long long)*gmax);
    v = gamtab[apos * 128 + f] / gm;
  }
  if (kind & 1) v *= sgn;
  pe[idx] = v;
}

// ---------------- fused q/k/v projection GEMM (grid.z picks input) ----------
#define GSTR 56
__launch_bounds__(256)
__global__ void proj3_kernel(const float* __restrict__ q_in, const float* __restrict__ k_in,
                             const float* __restrict__ v_in,
                             const float* __restrict__ Wq, const float* __restrict__ Wk,
                             const float* __restrict__ Wv,
                             u16* __restrict__ qh, u16* __restrict__ kh,
                             u16* __restrict__ vt){
  __shared__ u16 At[64 * GSTR];
  __shared__ u16 Wt[64 * GSTR];
  const int z = blockIdx.z;
  const float* A = (z == 0) ? q_in : (z == 1) ? k_in : v_in;
  const float* W = (z == 0) ? Wq : (z == 1) ? Wk : Wv;
  const float scale = (z == 0) ? 0.125f : 1.f;
  const int m0 = blockIdx.x * 64, n0 = blockIdx.y * 64;
  const int tid = threadIdx.x;
  const int w = tid >> 6, l = tid & 63, lr = l & 15, lg = l >> 4;
  const int moff = (w & 1) * 32, noff = (w >> 1) * 32;
  f32x4 acc[2][2] = {};
  const int arow = tid >> 2, akg = (tid & 3) * 8;
  const int wn = tid & 63, wkg = (tid >> 6) * 8;
  for (int k0 = 0; k0 < DM; k0 += 32){
    u16x8 av;
    {
      const float* ap = A + (size_t)(m0 + arow) * DM + k0 + akg;
      #pragma unroll
      for (int j = 0; j < 8; j++) av[j] = f2bf(ap[j]);
    }
    *(u16x8*)&At[arow * GSTR + akg] = av;
    u16x8 wv;
    #pragma unroll
    for (int i = 0; i < 8; i++)
      wv[i] = f2bf(W[(size_t)(k0 + wkg + i) * DM + n0 + wn]);
    *(u16x8*)&Wt[wn * GSTR + wkg] = wv;
    __syncthreads();
    u16x8 af0 = *(u16x8*)&At[(moff + lr) * GSTR + lg * 8];
    u16x8 af1 = *(u16x8*)&At[(moff + 16 + lr) * GSTR + lg * 8];
    u16x8 bf0 = *(u16x8*)&Wt[(noff + lr) * GSTR + lg * 8];
    u16x8 bf1 = *(u16x8*)&Wt[(noff + 16 + lr) * GSTR + lg * 8];
    acc[0][0] = MFMA(af0, bf0, acc[0][0]);
    acc[0][1] = MFMA(af0, bf1, acc[0][1]);
    acc[1][0] = MFMA(af1, bf0, acc[1][0]);
    acc[1][1] = MFMA(af1, bf1, acc[1][1]);
    __syncthreads();
  }
  u16* outb = (z == 0) ? qh : kh;
  #pragma unroll
  for (int mi = 0; mi < 2; mi++)
    #pragma unroll
    for (int ni = 0; ni < 2; ni++){
      if (z < 2){
        #pragma unroll
        for (int j = 0; j < 4; j++){
          int m = m0 + moff + mi * 16 + lg * 4 + j;
          int n = n0 + noff + ni * 16 + lr;
          outb[((size_t)(n >> 6) * LQ + m) * DH + (n & 63)] = f2bf(acc[mi][ni][j] * scale);
        }
      } else {
        int m = m0 + moff + mi * 16 + lg * 4;
        int n = n0 + noff + ni * 16 + lr;
        u16x4 ov;
        #pragma unroll
        for (int j = 0; j < 4; j++) ov[j] = f2bf(acc[mi][ni][j]);
        *(u16x4*)(vt + ((size_t)(n >> 6) * DH + (n & 63)) * LQ + m) = ov;
      }
    }
}

// ---------------- generic bf16-MFMA GEMM (rk + out-proj) ----------------
__launch_bounds__(256)
__global__ void gemm_kernel(const float* __restrict__ A, const float* __restrict__ W,
                            u16* __restrict__ outb, float* __restrict__ outf,
                            int M, float scale,
                            const float* __restrict__ bias, int mode){
  __shared__ u16 At[64 * GSTR];
  __shared__ u16 Wt[64 * GSTR];
  const int m0 = blockIdx.x * 64, n0 = blockIdx.y * 64;
  const int tid = threadIdx.x;
  const int w = tid >> 6, l = tid & 63, lr = l & 15, lg = l >> 4;
  const int moff = (w & 1) * 32, noff = (w >> 1) * 32;
  f32x4 acc[2][2] = {};
  const int arow = tid >> 2, akg = (tid & 3) * 8;
  const int wn = tid & 63, wkg = (tid >> 6) * 8;
  for (int k0 = 0; k0 < DM; k0 += 32){
    u16x8 av;
    if (m0 + arow < M){
      const float* ap = A + (size_t)(m0 + arow) * DM + k0 + akg;
      #pragma unroll
      for (int j = 0; j < 8; j++) av[j] = f2bf(ap[j]);
    } else {
      #pragma unroll
      for (int j = 0; j < 8; j++) av[j] = 0;
    }
    *(u16x8*)&At[arow * GSTR + akg] = av;
    u16x8 wv;
    #pragma unroll
    for (int i = 0; i < 8; i++)
      wv[i] = f2bf(W[(size_t)(k0 + wkg + i) * DM + n0 + wn]);
    *(u16x8*)&Wt[wn * GSTR + wkg] = wv;
    __syncthreads();
    u16x8 af0 = *(u16x8*)&At[(moff + lr) * GSTR + lg * 8];
    u16x8 af1 = *(u16x8*)&At[(moff + 16 + lr) * GSTR + lg * 8];
    u16x8 bf0 = *(u16x8*)&Wt[(noff + lr) * GSTR + lg * 8];
    u16x8 bf1 = *(u16x8*)&Wt[(noff + 16 + lr) * GSTR + lg * 8];
    acc[0][0] = MFMA(af0, bf0, acc[0][0]);
    acc[0][1] = MFMA(af0, bf1, acc[0][1]);
    acc[1][0] = MFMA(af1, bf0, acc[1][0]);
    acc[1][1] = MFMA(af1, bf1, acc[1][1]);
    __syncthreads();
  }
  #pragma unroll
  for (int mi = 0; mi < 2; mi++)
    #pragma unroll
    for (int ni = 0; ni < 2; ni++)
      #pragma unroll
      for (int j = 0; j < 4; j++){
        int m = m0 + moff + mi * 16 + lg * 4 + j;
        int n = n0 + noff + ni * 16 + lr;
        if (m < M){
          float v = acc[mi][ni][j] * scale;
          if (mode == 1){
            __builtin_nontemporal_store(v + bias[n], &outf[(size_t)m * DM + n]);
          } else {
            outb[((size_t)(n >> 6) * M + m) * DH + (n & 63)] = f2bf(v);
          }
        }
      }
}

// ---------------- fused rel-pos attention (r10 structure + NT map stores) ----
// Flat grid 1536, XCD-swizzled. One WG = 1 head x 16 q-rows, 8 waves; wave w
// owns k-slice [w*256,+256) + private band slab [16][280]. S in AGPRs.
// Map written with NONTEMPORAL stores (L2 bypass) — the 201 MB stream was
// write-allocate-thrashing L2/L3 and capping the kernel at ~1.1 TB/s.
#define QB 16
#define SSTR 280
#define SLAB (QB * SSTR)                       // u16 per wave slab
#define SMEM_ATTN (8 * SLAB * 2 + 1024)
__launch_bounds__(512, 4)
__global__ void attn_kernel(const u16* __restrict__ qh, const u16* __restrict__ kh,
                            const u16* __restrict__ vt, const u16* __restrict__ rk,
                            const int* __restrict__ mask,
                            const float* __restrict__ r_w, const float* __restrict__ r_r,
                            float* __restrict__ map, float* __restrict__ att){
  extern __shared__ char smem[];
  u16* RP = (u16*)smem;                         // 8 slabs
  float* redm = (float*)(smem + 8 * SLAB * 2);  // [8][16]
  float* redl = redm + 128;                     // [8][16]
  const int bid = blockIdx.x;
  const int swz = (bid & 7) * 192 + (bid >> 3); // XCD-aware: same head per XCD
  const int h = swz >> 7, q0 = (swz & 127) * QB;
  const int tid = threadIdx.x, w = tid >> 6, l = tid & 63, lr = l & 15, lg = l >> 4;
  const int roff = (LQ - 1) - q0 - (QB - 1);    // 2032 - q0
  const int kb = w * 256;
  u16* slab = RP + w * SLAB;

  // A fragments a1=(qh+r_w), a2=(qh+r_r)  (qh pre-scaled by 1/8)
  u16x8 a1[2], a2[2];
  #pragma unroll
  for (int kc = 0; kc < 2; kc++){
    u16x8 qv = *(const u16x8*)(qh + (size_t)(h * LQ + q0 + lr) * DH + kc * 32 + lg * 8);
    #pragma unroll
    for (int j = 0; j < 8; j++){
      int d = kc * 32 + lg * 8 + j;
      float f = bf2f(qv[j]);
      a1[kc][j] = f2bf(f + r_w[h * DH + d]);
      a2[kc][j] = f2bf(f + r_r[h * DH + d]);
    }
  }

  // loop 1: band slab — 17 tiles covering cols [kb, kb+272)
  #pragma unroll 4
  for (int t = 0; t < 17; t++){
    int r = roff + kb + t * 16 + lr;
    if (r > NR - 1) r = NR - 1;                 // never-gathered corner only
    const u16* rp = rk + (size_t)(h * NR + r) * DH + lg * 8;
    u16x8 b0 = *(const u16x8*)(rp);
    u16x8 b1 = *(const u16x8*)(rp + 32);
    f32x4 racc = {};
    racc = MFMA(a2[0], b0, racc);
    racc = MFMA(a2[1], b1, racc);
    #pragma unroll
    for (int j = 0; j < 4; j++)
      slab[(lg * 4 + j) * SSTR + t * 16 + lr] = f2bf(racc[j]);
  }
  __asm__ volatile("s_waitcnt lgkmcnt(0)" ::: "memory");   // wave-local slab ready
  __builtin_amdgcn_sched_barrier(0);

  // loop 2: content logits + wave-local band gather + mask -> S in AGPRs
  f32x4 s[16];
  #pragma unroll
  for (int nt = 0; nt < 16; nt++){
    const u16* kp = kh + (size_t)(h * LQ + kb + nt * 16 + lr) * DH + lg * 8;
    u16x8 b0 = *(const u16x8*)(kp);
    u16x8 b1 = *(const u16x8*)(kp + 32);
    f32x4 sv = {};
    sv = MFMA(a1[0], b0, sv);
    sv = MFMA(a1[1], b1, sv);
    int mv = mask[kb + nt * 16 + lr];
    #pragma unroll
    for (int j = 0; j < 4; j++){
      int ql = lg * 4 + j;
      float x = sv[j] + bf2f(slab[ql * SSTR + nt * 16 + lr + 15 - ql]);
      sv[j] = (mv == 1) ? -10000.f : x;
    }
    s[nt] = sv;
  }

  // softmax max reduce
  float fm[4];
  #pragma unroll
  for (int j = 0; j < 4; j++){
    float mx = -3.0e38f;
    #pragma unroll
    for (int nt = 0; nt < 16; nt++) mx = fmaxf(mx, s[nt][j]);
    #pragma unroll
    for (int off = 1; off < 16; off <<= 1) mx = fmaxf(mx, __shfl_xor(mx, off));
    if (lr == 0) redm[w * QB + lg * 4 + j] = mx;
  }
  __syncthreads();
  #pragma unroll
  for (int j = 0; j < 4; j++){
    int ql = lg * 4 + j;
    float mx = redm[ql];
    #pragma unroll
    for (int w2 = 1; w2 < 8; w2++) mx = fmaxf(mx, redm[w2 * QB + ql]);
    fm[j] = mx;
  }

  // exp + P store (overwrites band in own slab; band fully consumed)
  float ls[4] = {0.f, 0.f, 0.f, 0.f};
  #pragma unroll
  for (int nt = 0; nt < 16; nt++)
    #pragma unroll
    for (int j = 0; j < 4; j++){
      float p = __expf(s[nt][j] - fm[j]);
      ls[j] += p;
      slab[(lg * 4 + j) * SSTR + nt * 16 + lr] = f2bf(p);
    }
  #pragma unroll
  for (int j = 0; j < 4; j++){
    float sum = ls[j];
    #pragma unroll
    for (int off = 1; off < 16; off <<= 1) sum += __shfl_xor(sum, off);
    if (lr == 0) redl[w * QB + lg * 4 + j] = sum;
  }
  __syncthreads();
  float inv[4];
  #pragma unroll
  for (int j = 0; j < 4; j++){
    int ql = lg * 4 + j;
    float d = redl[ql];
    #pragma unroll
    for (int w2 = 1; w2 < 8; w2++) d += redl[w2 * QB + ql];
    inv[j] = 1.f / d;
  }

  // normalized map write (NONTEMPORAL f32 stores, output 1) — before PV so
  // stores drain under the PV MFMAs; nt flag bypasses L2 allocation.
  {
    int qrow = tid >> 5, cb = (tid & 31) * 8;
    float dsum = redl[qrow];
    #pragma unroll
    for (int w2 = 1; w2 < 8; w2++) dsum += redl[w2 * QB + qrow];
    float invr = 1.f / dsum;
    float* mrow = map + (size_t)(h * LQ + q0 + qrow) * LQ;
    #pragma unroll
    for (int it = 0; it < 8; it++){
      u16x8 pv = *(u16x8*)&RP[it * SLAB + qrow * SSTR + cb];
      f32x4 o0, o1;
      #pragma unroll
      for (int j = 0; j < 4; j++){
        o0[j] = bf2f(pv[j]) * invr;
        o1[j] = bf2f(pv[4 + j]) * invr;
      }
      int c = cb + it * 256;
      __builtin_nontemporal_store(o0, (f32x4*)(mrow + c));
      __builtin_nontemporal_store(o1, (f32x4*)(mrow + c + 4));
    }
  }

  // PV (A-frags = P rows from own slab, B-frags = vt[h][d][k] contiguous)
  f32x4 o[4] = {};
  #pragma unroll
  for (int kc2 = 0; kc2 < 8; kc2++){
    u16x8 pa = *(u16x8*)&slab[lr * SSTR + kc2 * 32 + lg * 8];
    #pragma unroll
    for (int ni = 0; ni < 4; ni++){
      u16x8 vv = *(const u16x8*)(vt + (size_t)(h * DH + ni * 16 + lr) * LQ + kb + kc2 * 32 + lg * 8);
      o[ni] = MFMA(pa, vv, o[ni]);
    }
  }
  __syncthreads();

  // cross-wave O reduction (overlays slabs)
  float* Op = (float*)smem;    // [8][16][64]
  #pragma unroll
  for (int ni = 0; ni < 4; ni++)
    #pragma unroll
    for (int j = 0; j < 4; j++)
      Op[(w * QB + lg * 4 + j) * 64 + ni * 16 + lr] = o[ni][j] * inv[j];
  __syncthreads();
  {
    int q = tid >> 5, dg = (tid & 31) * 2;
    float acc0 = 0.f, acc1 = 0.f;
    #pragma unroll
    for (int w2 = 0; w2 < 8; w2++){
      acc0 += Op[(w2 * QB + q) * 64 + dg];
      acc1 += Op[(w2 * QB + q) * 64 + dg + 1];
    }
    float* ap = att + (size_t)(q0 + q) * DM + h * DH + dg;
    ap[0] = acc0;
    ap[1] = acc1;
  }
}

extern "C" void kernel_launch(void* const* d_in, const int* in_sizes, int n_in,
                              void* d_out, int out_size, void* d_ws, size_t ws_size,
                              hipStream_t stream){
  const float* v_in = (const float*)d_in[0];
  const float* k_in = (const float*)d_in[1];
  const float* q_in = (const float*)d_in[2];
  const int*   mask = (const int*)d_in[3];
  const float* Wq   = (const float*)d_in[4];
  const float* Wk   = (const float*)d_in[5];
  const float* Wv   = (const float*)d_in[6];
  const float* Wrk  = (const float*)d_in[7];
  const float* r_w  = (const float*)d_in[8];
  const float* r_r  = (const float*)d_in[9];
  const float* Wo   = (const float*)d_in[10];
  const float* bo   = (const float*)d_in[11];

  char* ws = (char*)d_ws;
  u16* qh = (u16*)(ws + 0);              // [12][2048][64] bf16
  u16* kh = (u16*)(ws + 3145728);
  u16* vt = (u16*)(ws + 6291456);        // [12][64][2048] bf16
  u16* rk = (u16*)(ws + 9437184);        // [12][4095][64] bf16
  float* pe = (float*)(ws + 15727104);   // [4095][768] f32
  float* att = (float*)(ws + 28306944);  // [2048][768] f32
  float* gamtab = (float*)(ws + 34598400);           // [2048][128] f32
  unsigned long long* gmax = (unsigned long long*)(ws + 35646976);

  float* out0 = (float*)d_out;                     // [2048][768] f32
  float* map  = out0 + (size_t)LQ * DM;            // [12][2048][2048] f32

  hipMemsetAsync(gmax, 0, 8, stream);
  gamma_probs_kernel<<<1024, 256, 0, stream>>>(gamtab, gmax);
  pe_kernel<<<(NR * DM + 255) / 256, 256, 0, stream>>>(gamtab, gmax, pe);

  proj3_kernel<<<dim3(32, 12, 3), 256, 0, stream>>>(q_in, k_in, v_in, Wq, Wk, Wv,
                                                    qh, kh, vt);
  gemm_kernel<<<dim3(64, 12), 256, 0, stream>>>(pe, Wrk, rk, nullptr, NR, 1.f, nullptr, 0);

  hipFuncSetAttribute((const void*)attn_kernel,
                      hipFuncAttributeMaxDynamicSharedMemorySize, SMEM_ATTN);
  attn_kernel<<<dim3((LQ / QB) * NH), 512, SMEM_ATTN, stream>>>(qh, kh, vt, rk, mask,
                                                                r_w, r_r, map, att);
  gemm_kernel<<<dim3(32, 12), 256, 0, stream>>>(att, Wo, nullptr, out0, LQ, 1.f, bo, 1);
}